// Round 1
// baseline (3931.344 us; speedup 1.0000x reference)
//
#include <hip/hip_runtime.h>
#include <stdint.h>

typedef __bf16 bf16_t;
typedef __attribute__((ext_vector_type(8))) __bf16 bf16x8;
typedef __attribute__((ext_vector_type(4))) __bf16 bf16x4;
typedef __attribute__((ext_vector_type(4))) float f32x4;

#define NB 32
#define NS 2048
#define ND 1024
#define NV 32000
#define SP 2050   // padded rows per batch for conv (1 zero row each side)

__device__ __forceinline__ float sigmoid_(float x) { return 1.0f / (1.0f + __expf(-x)); }

__device__ __forceinline__ void gload_lds16(const void* g, void* lds) {
  __builtin_amdgcn_global_load_lds((const __attribute__((address_space(1))) void*)g,
                                   (__attribute__((address_space(3))) void*)lds, 16, 0, 0);
}

// ---------------- prep / elementwise kernels ----------------

__global__ void zero_pad_k(bf16_t* h0p) {
  int i = blockIdx.x;  // 0..63 : 2 pad rows per batch
  int b = i >> 1;
  size_t row = (size_t)b * SP + ((i & 1) ? (SP - 1) : 0);
  bf16x4 z = {};
  *(bf16x4*)(h0p + row * ND + threadIdx.x * 4) = z;
}

__global__ void embed_k(const int* __restrict__ x, const float* __restrict__ emb,
                        const float* __restrict__ pos, bf16_t* __restrict__ h0p) {
  int bs = blockIdx.x;  // 0..NB*NS-1
  int b = bs >> 11, s = bs & (NS - 1);
  int idx = x[bs];
  const float* e = emb + (size_t)idx * ND;
  const float* p = pos + (size_t)s * ND;
  bf16_t* o = h0p + ((size_t)b * SP + s + 1) * ND;
  int d = threadIdx.x * 4;
  f32x4 ev = *(const f32x4*)(e + d);
  f32x4 pv = *(const f32x4*)(p + d);
  bf16x4 ov;
  ov[0] = (bf16_t)(ev[0] + pv[0]);
  ov[1] = (bf16_t)(ev[1] + pv[1]);
  ov[2] = (bf16_t)(ev[2] + pv[2]);
  ov[3] = (bf16_t)(ev[3] + pv[3]);
  *(bf16x4*)(o + d) = ov;
}

// f32 (R x C) -> bf16 (C x R) transpose+convert, 32x32 LDS tiles
__global__ void conv_transpose_k(const float* __restrict__ in, bf16_t* __restrict__ out,
                                 int R, int C) {
  __shared__ float tile[32][33];
  int tc = blockIdx.x * 32, tr = blockIdx.y * 32;
  int tx = threadIdx.x;
  for (int i = threadIdx.y; i < 32; i += 8)
    tile[i][tx] = in[(size_t)(tr + i) * C + tc + tx];
  __syncthreads();
  for (int i = threadIdx.y; i < 32; i += 8)
    out[(size_t)(tc + i) * R + tr + tx] = (bf16_t)tile[tx][i];
}

__global__ void dup_row_k(bf16_t* nodes) {
  int b = blockIdx.x;
  const bf16_t* src = nodes + ((size_t)b * NS + NS - 2) * ND;
  bf16_t* dst = nodes + ((size_t)b * NS + NS - 1) * ND;
  int d = threadIdx.x * 4;
  *(bf16x4*)(dst + d) = *(const bf16x4*)(src + d);
}

// ---------------- GEMM: C = A(MxK, lda) @ Bt(NxK)^T + bias, epilogues ----------------
// EPI 0: bf16 store       1: bf16 aux*sigmoid(v) (GLU, aux bf16)
// EPI 2: f32 store        3: f32 sigmoid(v)       4: f32 aux*sigmoid(v) (aux f32, may alias Cout)
template <int EPI>
__global__ __launch_bounds__(256, 2) void gemm_bt(
    const bf16_t* __restrict__ A, const bf16_t* __restrict__ Bt,
    const float* __restrict__ bias, const void* aux, void* Cout,
    int M, int N, int K, int lda, int batchShift, int batchPad) {
  const int tid = threadIdx.x;
  const int lane = tid & 63;
  const int wave = tid >> 6;
  const int m0 = blockIdx.x * 128;
  const int n0 = blockIdx.y * 128;
  const int waveM = wave >> 1, waveN = wave & 1;

  __shared__ __align__(16) bf16_t sA[128 * 32];
  __shared__ __align__(16) bf16_t sB[128 * 32];

  f32x4 acc[4][4] = {};

  const int sr = tid >> 2;          // 0..63
  const int sc = (tid & 3) * 8;     // k elem offset within 32
  bf16_t* ldsA = &sA[(wave * 16) * 32];  // wave-uniform base
  bf16_t* ldsB = &sB[(wave * 16) * 32];

  for (int k0 = 0; k0 < K; k0 += 32) {
#pragma unroll
    for (int j = 0; j < 2; ++j) {
      int gm = m0 + j * 64 + sr;
      if (gm > M - 1) gm = M - 1;
      int grow = gm + (gm >> batchShift) * batchPad;  // conv row remap (pad==0 -> identity)
      gload_lds16(A + (size_t)grow * lda + (k0 + sc), ldsA + (size_t)j * 2048);
      int gn = n0 + j * 64 + sr;
      gload_lds16(Bt + (size_t)gn * K + (k0 + sc), ldsB + (size_t)j * 2048);
    }
    __syncthreads();

    bf16x8 af[4], bfr[4];
#pragma unroll
    for (int i = 0; i < 4; ++i) {
      int r = waveM * 64 + i * 16 + (lane & 15);
      af[i] = *(const bf16x8*)&sA[r * 32 + (lane >> 4) * 8];
    }
#pragma unroll
    for (int j = 0; j < 4; ++j) {
      int r = waveN * 64 + j * 16 + (lane & 15);
      bfr[j] = *(const bf16x8*)&sB[r * 32 + (lane >> 4) * 8];
    }
#pragma unroll
    for (int i = 0; i < 4; ++i)
#pragma unroll
      for (int j = 0; j < 4; ++j)
        acc[i][j] = __builtin_amdgcn_mfma_f32_16x16x32_bf16(af[i], bfr[j], acc[i][j], 0, 0, 0);
    __syncthreads();
  }

  const int colBase = n0 + waveN * 64 + (lane & 15);
#pragma unroll
  for (int i = 0; i < 4; ++i) {
    const int rowBase = m0 + waveM * 64 + i * 16 + (lane >> 4) * 4;
#pragma unroll
    for (int j = 0; j < 4; ++j) {
      const int col = colBase + j * 16;
      const float bv = bias[col];
#pragma unroll
      for (int r = 0; r < 4; ++r) {
        const int row = rowBase + r;
        if (row >= M) continue;
        float v = acc[i][j][r] + bv;
        size_t o = (size_t)row * N + col;
        if constexpr (EPI == 0) {
          ((bf16_t*)Cout)[o] = (bf16_t)v;
        } else if constexpr (EPI == 1) {
          float hh = (float)((const bf16_t*)aux)[o];
          ((bf16_t*)Cout)[o] = (bf16_t)(hh * sigmoid_(v));
        } else if constexpr (EPI == 2) {
          ((float*)Cout)[o] = v;
        } else if constexpr (EPI == 3) {
          ((float*)Cout)[o] = sigmoid_(v);
        } else {
          float val = ((const float*)aux)[o];
          ((float*)Cout)[o] = val * sigmoid_(v);
        }
      }
    }
  }
}

// ---------------- tree combine: rmsnorm + gated mix ----------------
__global__ __launch_bounds__(256) void tree_combine_k(
    const float* __restrict__ vg, const float* __restrict__ rgs,
    const bf16_t* __restrict__ cur, const float* __restrict__ rms_w,
    bf16_t* __restrict__ outb) {
  const int m = blockIdx.x;
  const int t = threadIdx.x;
  const int d = t * 4;
  f32x4 v = *(const f32x4*)(vg + (size_t)m * ND + d);
  float ss = v[0] * v[0] + v[1] * v[1] + v[2] * v[2] + v[3] * v[3];
#pragma unroll
  for (int o = 32; o > 0; o >>= 1) ss += __shfl_xor(ss, o);
  __shared__ float red[4];
  if ((t & 63) == 0) red[t >> 6] = ss;
  __syncthreads();
  float ms = (red[0] + red[1] + red[2] + red[3]) * (1.0f / ND);
  float scale = rsqrtf(ms + 1.1920929e-07f);
  f32x4 g = *(const f32x4*)(rgs + (size_t)m * ND + d);
  f32x4 w = *(const f32x4*)(rms_w + d);
  const bf16_t* c0 = cur + (size_t)m * 2048;
  bf16x4 lv = *(const bf16x4*)(c0 + d);
  bf16x4 rv = *(const bf16x4*)(c0 + ND + d);
  bf16x4 o4;
#pragma unroll
  for (int k = 0; k < 4; ++k) {
    float merged = v[k] * scale * w[k];
    float resid = 0.5f * ((float)lv[k] + (float)rv[k]);
    o4[k] = (bf16_t)(g[k] * merged + (1.0f - g[k]) * resid);
  }
  *(bf16x4*)(outb + (size_t)m * ND + d) = o4;
}

__global__ void build_ctx_k(const bf16_t* __restrict__ root, const bf16_t* __restrict__ nodes,
                            float* __restrict__ ctx) {
  int b = blockIdx.x, t = threadIdx.x;
  const bf16_t* r = root + (size_t)b * ND;
  const bf16_t* l = nodes + ((size_t)b * NS + NS - 2) * ND;
  int d = t * 4;
#pragma unroll
  for (int k = 0; k < 4; ++k) {
    ctx[(size_t)b * 2048 + d + k] = (float)r[d + k];
    ctx[(size_t)b * 2048 + ND + d + k] = (float)l[d + k];
  }
}

// ---------------- final projection in f32: out[b,v] = ctx[b,:]@wp[:,v] + bp[v] ----------------
__global__ __launch_bounds__(256) void final_proj_k(
    const float* __restrict__ ctx, const float* __restrict__ wp,
    const float* __restrict__ bp, float* __restrict__ out) {
  const int v = blockIdx.x * 256 + threadIdx.x;
  float acc[NB];
#pragma unroll
  for (int b = 0; b < NB; ++b) acc[b] = 0.f;
  __shared__ float sctx[NB][128];
  for (int k0 = 0; k0 < 2048; k0 += 128) {
    __syncthreads();
    for (int i = threadIdx.x; i < NB * 128; i += 256) {
      int bb = i >> 7, kk = i & 127;
      sctx[bb][kk] = ctx[(size_t)bb * 2048 + k0 + kk];
    }
    __syncthreads();
    for (int kk = 0; kk < 128; ++kk) {
      float wv = wp[(size_t)(k0 + kk) * NV + v];
#pragma unroll
      for (int b = 0; b < NB; ++b) acc[b] += sctx[b][kk] * wv;
    }
  }
#pragma unroll
  for (int b = 0; b < NB; ++b) out[(size_t)b * NV + v] = acc[b] + bp[v];
}

// ---------------- launch ----------------
extern "C" void kernel_launch(void* const* d_in, const int* in_sizes, int n_in,
                              void* d_out, int out_size, void* d_ws, size_t ws_size,
                              hipStream_t stream) {
  const int* x = (const int*)d_in[0];
  const float* emb = (const float*)d_in[1];
  const float* pos = (const float*)d_in[2];
  const float* conv_w = (const float*)d_in[3];
  const float* conv_b = (const float*)d_in[4];
  const float* wg1 = (const float*)d_in[5];
  const float* bg1 = (const float*)d_in[6];
  const float* wmv = (const float*)d_in[7];
  const float* bmv = (const float*)d_in[8];
  const float* wmg = (const float*)d_in[9];
  const float* bmg = (const float*)d_in[10];
  const float* wrg = (const float*)d_in[11];
  const float* brg = (const float*)d_in[12];
  const float* rms_w = (const float*)d_in[13];
  const float* wp = (const float*)d_in[14];
  const float* bp = (const float*)d_in[15];
  float* out = (float*)d_out;

  char* ws = (char*)d_ws;
  size_t off = 0;
  auto alloc = [&](size_t bytes) -> void* {
    void* p = ws + off;
    off += (bytes + 255) & ~(size_t)255;
    return p;
  };
  bf16_t* h0p = (bf16_t*)alloc((size_t)NB * SP * ND * 2);    // conv input, padded
  bf16_t* h = (bf16_t*)alloc((size_t)NB * NS * ND * 2);      // conv output
  bf16_t* nodes = (bf16_t*)alloc((size_t)NB * NS * ND * 2);  // gated nodes (row 2047 dup'd)
  bf16_t* tb0 = (bf16_t*)alloc((size_t)NB * 1024 * ND * 2);
  bf16_t* tb1 = (bf16_t*)alloc((size_t)NB * 1024 * ND * 2);
  bf16_t* convT = (bf16_t*)alloc((size_t)ND * 3072 * 2);
  bf16_t* wg1T = (bf16_t*)alloc((size_t)ND * 1024 * 2);
  bf16_t* wmvT = (bf16_t*)alloc((size_t)ND * 2048 * 2);
  bf16_t* wmgT = (bf16_t*)alloc((size_t)ND * 2048 * 2);
  bf16_t* wrgT = (bf16_t*)alloc((size_t)ND * 2048 * 2);
  float* ctx = (float*)alloc((size_t)NB * 2048 * 4);
  if (off > ws_size) return;  // workspace too small: bail (will fail validation visibly)
  float* valbuf = (float*)h;   // alias: h dead after gate GEMM; 128MB f32 fits exactly
  float* rgbuf = (float*)h0p;  // alias: h0p dead after conv GEMM

  dim3 t256(256), tb32(32, 8);

  // weight conversions (transpose to N x K bf16)
  conv_transpose_k<<<dim3(ND / 32, 3072 / 32), tb32, 0, stream>>>(conv_w, convT, 3072, ND);
  conv_transpose_k<<<dim3(ND / 32, ND / 32), tb32, 0, stream>>>(wg1, wg1T, ND, ND);
  conv_transpose_k<<<dim3(ND / 32, 2048 / 32), tb32, 0, stream>>>(wmv, wmvT, 2048, ND);
  conv_transpose_k<<<dim3(ND / 32, 2048 / 32), tb32, 0, stream>>>(wmg, wmgT, 2048, ND);
  conv_transpose_k<<<dim3(ND / 32, 2048 / 32), tb32, 0, stream>>>(wrg, wrgT, 2048, ND);

  zero_pad_k<<<64, t256, 0, stream>>>(h0p);
  embed_k<<<NB * NS, t256, 0, stream>>>(x, emb, pos, h0p);

  // conv as GEMM over contiguous 3*D windows of padded buffer (row remap: +2 per batch)
  gemm_bt<0><<<dim3(512, 8), t256, 0, stream>>>(h0p, convT, conv_b, nullptr, h,
                                                NB * NS, ND, 3072, ND, 11, 2);
  // nodes = h * sigmoid(h@wg1 + bg1)
  gemm_bt<1><<<dim3(512, 8), t256, 0, stream>>>(h, wg1T, bg1, h, nodes,
                                                NB * NS, ND, ND, ND, 0, 0);
  dup_row_k<<<NB, t256, 0, stream>>>(nodes);  // pad odd level: row 2047 := row 2046

  const bf16_t* cur = nodes;
  bf16_t* bufs[2] = {tb0, tb1};
  int pp = 0;
  for (int L = NS; L > 1; L >>= 1) {
    int M = NB * (L / 2);
    dim3 g((M + 127) / 128, 8);
    gemm_bt<2><<<g, t256, 0, stream>>>(cur, wmvT, bmv, nullptr, valbuf, M, ND, 2048, 2048, 0, 0);
    gemm_bt<4><<<g, t256, 0, stream>>>(cur, wmgT, bmg, valbuf, valbuf, M, ND, 2048, 2048, 0, 0);
    gemm_bt<3><<<g, t256, 0, stream>>>(cur, wrgT, brg, nullptr, rgbuf, M, ND, 2048, 2048, 0, 0);
    tree_combine_k<<<M, t256, 0, stream>>>(valbuf, rgbuf, cur, rms_w, bufs[pp]);
    cur = bufs[pp];
    pp ^= 1;
  }

  build_ctx_k<<<NB, t256, 0, stream>>>(cur, nodes, ctx);
  final_proj_k<<<NV / 256, t256, 0, stream>>>(ctx, wp, bp, out);
}

// Round 2
// 2998.478 us; speedup vs baseline: 1.3111x; 1.3111x over previous
//
#include <hip/hip_runtime.h>
#include <stdint.h>

typedef __bf16 bf16_t;
typedef __attribute__((ext_vector_type(8))) __bf16 bf16x8;
typedef __attribute__((ext_vector_type(4))) __bf16 bf16x4;
typedef __attribute__((ext_vector_type(4))) float f32x4;

#define NB 32
#define NS 2048
#define ND 1024
#define NV 32000
#define SP 2050   // padded rows per batch for conv (1 zero row each side)
#define MCHUNK 16384  // max rows per fused tree-GEMM chunk (201MB f32 output)

__device__ __forceinline__ float sigmoid_(float x) { return 1.0f / (1.0f + __expf(-x)); }

__device__ __forceinline__ void gload_lds16(const void* g, void* lds) {
  __builtin_amdgcn_global_load_lds((const __attribute__((address_space(1))) void*)g,
                                   (__attribute__((address_space(3))) void*)lds, 16, 0, 0);
}

// ---------------- prep / elementwise kernels ----------------

__global__ void zero_pad_k(bf16_t* h0p) {
  int i = blockIdx.x;  // 0..63 : 2 pad rows per batch
  int b = i >> 1;
  size_t row = (size_t)b * SP + ((i & 1) ? (SP - 1) : 0);
  bf16x4 z = {};
  *(bf16x4*)(h0p + row * ND + threadIdx.x * 4) = z;
}

__global__ void embed_k(const int* __restrict__ x, const float* __restrict__ emb,
                        const float* __restrict__ pos, bf16_t* __restrict__ h0p) {
  int bs = blockIdx.x;  // 0..NB*NS-1
  int b = bs >> 11, s = bs & (NS - 1);
  int idx = x[bs];
  const float* e = emb + (size_t)idx * ND;
  const float* p = pos + (size_t)s * ND;
  bf16_t* o = h0p + ((size_t)b * SP + s + 1) * ND;
  int d = threadIdx.x * 4;
  f32x4 ev = *(const f32x4*)(e + d);
  f32x4 pv = *(const f32x4*)(p + d);
  bf16x4 ov;
  ov[0] = (bf16_t)(ev[0] + pv[0]);
  ov[1] = (bf16_t)(ev[1] + pv[1]);
  ov[2] = (bf16_t)(ev[2] + pv[2]);
  ov[3] = (bf16_t)(ev[3] + pv[3]);
  *(bf16x4*)(o + d) = ov;
}

// f32 (R x C) -> bf16 (C x R) transpose+convert, 32x32 LDS tiles
__global__ void conv_transpose_k(const float* __restrict__ in, bf16_t* __restrict__ out,
                                 int R, int C) {
  __shared__ float tile[32][33];
  int tc = blockIdx.x * 32, tr = blockIdx.y * 32;
  int tx = threadIdx.x;
  for (int i = threadIdx.y; i < 32; i += 8)
    tile[i][tx] = in[(size_t)(tr + i) * C + tc + tx];
  __syncthreads();
  for (int i = threadIdx.y; i < 32; i += 8)
    out[(size_t)(tc + i) * R + tr + tx] = (bf16_t)tile[tx][i];
}

__global__ void dup_row_k(bf16_t* nodes) {
  int b = blockIdx.x;
  const bf16_t* src = nodes + ((size_t)b * NS + NS - 2) * ND;
  bf16_t* dst = nodes + ((size_t)b * NS + NS - 1) * ND;
  int d = threadIdx.x * 4;
  *(bf16x4*)(dst + d) = *(const bf16x4*)(src + d);
}

__global__ void concat3_k(const float* __restrict__ a, const float* __restrict__ b,
                          const float* __restrict__ c, float* __restrict__ o) {
  int i = blockIdx.x * 256 + threadIdx.x;  // 0..3071
  o[i] = i < 1024 ? a[i] : (i < 2048 ? b[i - 1024] : c[i - 2048]);
}

// ---------------- GEMM: C = A(MxK, lda) @ Bt(NxK)^T + bias ----------------
// blockIdx.x = N-block (inner, shares A panel), blockIdx.y = M-block.
// EPI 0: bf16 store   1: bf16 aux*sigmoid(v) (GLU, aux bf16)   2: f32 store
template <int EPI>
__global__ __launch_bounds__(256, 2) void gemm_bt(
    const bf16_t* __restrict__ A, const bf16_t* __restrict__ Bt,
    const float* __restrict__ bias, const void* aux, void* Cout,
    int M, int N, int K, int lda, int batchShift, int batchPad) {
  const int tid = threadIdx.x;
  const int lane = tid & 63;
  const int wave = tid >> 6;
  const int n0 = blockIdx.x * 128;
  const int m0 = blockIdx.y * 128;
  const int waveM = wave >> 1, waveN = wave & 1;

  __shared__ __align__(16) bf16_t sA[128 * 32];
  __shared__ __align__(16) bf16_t sB[128 * 32];

  f32x4 acc[4][4] = {};

  const int sr = tid >> 2;          // 0..63
  const int sc = (tid & 3) * 8;     // k elem offset within 32
  bf16_t* ldsA = &sA[(wave * 16) * 32];  // wave-uniform base
  bf16_t* ldsB = &sB[(wave * 16) * 32];

  for (int k0 = 0; k0 < K; k0 += 32) {
#pragma unroll
    for (int j = 0; j < 2; ++j) {
      int gm = m0 + j * 64 + sr;
      if (gm > M - 1) gm = M - 1;
      int grow = gm + (gm >> batchShift) * batchPad;  // conv row remap (pad==0 -> identity)
      gload_lds16(A + (size_t)grow * lda + (k0 + sc), ldsA + (size_t)j * 2048);
      int gn = n0 + j * 64 + sr;
      gload_lds16(Bt + (size_t)gn * K + (k0 + sc), ldsB + (size_t)j * 2048);
    }
    __syncthreads();

    bf16x8 af[4], bfr[4];
#pragma unroll
    for (int i = 0; i < 4; ++i) {
      int r = waveM * 64 + i * 16 + (lane & 15);
      af[i] = *(const bf16x8*)&sA[r * 32 + (lane >> 4) * 8];
    }
#pragma unroll
    for (int j = 0; j < 4; ++j) {
      int r = waveN * 64 + j * 16 + (lane & 15);
      bfr[j] = *(const bf16x8*)&sB[r * 32 + (lane >> 4) * 8];
    }
#pragma unroll
    for (int i = 0; i < 4; ++i)
#pragma unroll
      for (int j = 0; j < 4; ++j)
        acc[i][j] = __builtin_amdgcn_mfma_f32_16x16x32_bf16(af[i], bfr[j], acc[i][j], 0, 0, 0);
    __syncthreads();
  }

  const int colBase = n0 + waveN * 64 + (lane & 15);
#pragma unroll
  for (int i = 0; i < 4; ++i) {
    const int rowBase = m0 + waveM * 64 + i * 16 + (lane >> 4) * 4;
#pragma unroll
    for (int j = 0; j < 4; ++j) {
      const int col = colBase + j * 16;
      const float bv = bias[col];
#pragma unroll
      for (int r = 0; r < 4; ++r) {
        const int row = rowBase + r;
        if (row >= M) continue;
        float v = acc[i][j][r] + bv;
        size_t o = (size_t)row * N + col;
        if constexpr (EPI == 0) {
          ((bf16_t*)Cout)[o] = (bf16_t)v;
        } else if constexpr (EPI == 1) {
          float hh = (float)((const bf16_t*)aux)[o];
          ((bf16_t*)Cout)[o] = (bf16_t)(hh * sigmoid_(v));
        } else {
          ((float*)Cout)[o] = v;
        }
      }
    }
  }
}

// ---------------- tree combine: rmsnorm + gated mix, sigmoids from fused logits ----------------
// fb layout per row: [0,1024) = val, [1024,2048) = mg logit, [2048,3072) = rg logit
__global__ __launch_bounds__(256) void tree_combine_k(
    const float* __restrict__ fb, const bf16_t* __restrict__ cur,
    const float* __restrict__ rms_w, bf16_t* __restrict__ outb) {
  const int m = blockIdx.x;
  const int t = threadIdx.x;
  const int d = t * 4;
  const float* row = fb + (size_t)m * 3072;
  f32x4 v = *(const f32x4*)(row + d);
  f32x4 gl = *(const f32x4*)(row + 1024 + d);
  f32x4 rl = *(const f32x4*)(row + 2048 + d);
  f32x4 vg;
#pragma unroll
  for (int k = 0; k < 4; ++k) vg[k] = v[k] * sigmoid_(gl[k]);
  float ss = vg[0] * vg[0] + vg[1] * vg[1] + vg[2] * vg[2] + vg[3] * vg[3];
#pragma unroll
  for (int o = 32; o > 0; o >>= 1) ss += __shfl_xor(ss, o);
  __shared__ float red[4];
  if ((t & 63) == 0) red[t >> 6] = ss;
  __syncthreads();
  float ms = (red[0] + red[1] + red[2] + red[3]) * (1.0f / ND);
  float scale = rsqrtf(ms + 1.1920929e-07f);
  f32x4 w = *(const f32x4*)(rms_w + d);
  const bf16_t* c0 = cur + (size_t)m * 2048;
  bf16x4 lv = *(const bf16x4*)(c0 + d);
  bf16x4 rv = *(const bf16x4*)(c0 + ND + d);
  bf16x4 o4;
#pragma unroll
  for (int k = 0; k < 4; ++k) {
    float merged = vg[k] * scale * w[k];
    float resid = 0.5f * ((float)lv[k] + (float)rv[k]);
    float g = sigmoid_(rl[k]);
    o4[k] = (bf16_t)(g * merged + (1.0f - g) * resid);
  }
  *(bf16x4*)(outb + (size_t)m * ND + d) = o4;
}

__global__ void build_ctx_k(const bf16_t* __restrict__ root, const bf16_t* __restrict__ nodes,
                            float* __restrict__ ctx) {
  int b = blockIdx.x, t = threadIdx.x;
  const bf16_t* r = root + (size_t)b * ND;
  const bf16_t* l = nodes + ((size_t)b * NS + NS - 2) * ND;
  int d = t * 4;
#pragma unroll
  for (int k = 0; k < 4; ++k) {
    ctx[(size_t)b * 2048 + d + k] = (float)r[d + k];
    ctx[(size_t)b * 2048 + ND + d + k] = (float)l[d + k];
  }
}

// ---------------- final projection in f32: out[b,v] = ctx[b,:]@wp[:,v] + bp[v] ----------------
__global__ __launch_bounds__(256) void final_proj_k(
    const float* __restrict__ ctx, const float* __restrict__ wp,
    const float* __restrict__ bp, float* __restrict__ out) {
  const int v = blockIdx.x * 256 + threadIdx.x;
  float acc[NB];
#pragma unroll
  for (int b = 0; b < NB; ++b) acc[b] = 0.f;
  __shared__ float sctx[NB][128];
  for (int k0 = 0; k0 < 2048; k0 += 128) {
    __syncthreads();
    for (int i = threadIdx.x; i < NB * 128; i += 256) {
      int bb = i >> 7, kk = i & 127;
      sctx[bb][kk] = ctx[(size_t)bb * 2048 + k0 + kk];
    }
    __syncthreads();
    for (int kk = 0; kk < 128; ++kk) {
      float wv = wp[(size_t)(k0 + kk) * NV + v];
#pragma unroll
      for (int b = 0; b < NB; ++b) acc[b] += sctx[b][kk] * wv;
    }
  }
#pragma unroll
  for (int b = 0; b < NB; ++b) out[(size_t)b * NV + v] = acc[b] + bp[v];
}

// ---------------- launch ----------------
extern "C" void kernel_launch(void* const* d_in, const int* in_sizes, int n_in,
                              void* d_out, int out_size, void* d_ws, size_t ws_size,
                              hipStream_t stream) {
  const int* x = (const int*)d_in[0];
  const float* emb = (const float*)d_in[1];
  const float* pos = (const float*)d_in[2];
  const float* conv_w = (const float*)d_in[3];
  const float* conv_b = (const float*)d_in[4];
  const float* wg1 = (const float*)d_in[5];
  const float* bg1 = (const float*)d_in[6];
  const float* wmv = (const float*)d_in[7];
  const float* bmv = (const float*)d_in[8];
  const float* wmg = (const float*)d_in[9];
  const float* bmg = (const float*)d_in[10];
  const float* wrg = (const float*)d_in[11];
  const float* brg = (const float*)d_in[12];
  const float* rms_w = (const float*)d_in[13];
  const float* wp = (const float*)d_in[14];
  const float* bp = (const float*)d_in[15];
  float* out = (float*)d_out;

  char* ws = (char*)d_ws;
  size_t off = 0;
  auto alloc = [&](size_t bytes) -> void* {
    void* p = ws + off;
    off += (bytes + 255) & ~(size_t)255;
    return p;
  };
  bf16_t* h0p = (bf16_t*)alloc((size_t)NB * SP * ND * 2);    // conv input, padded
  bf16_t* h = (bf16_t*)alloc((size_t)NB * NS * ND * 2);      // conv output
  bf16_t* nodes = (bf16_t*)alloc((size_t)NB * NS * ND * 2);  // gated nodes (row 2047 dup'd)
  bf16_t* tb0 = (bf16_t*)alloc((size_t)NB * 1024 * ND * 2);
  bf16_t* tb1 = (bf16_t*)alloc((size_t)NB * 1024 * ND * 2);
  bf16_t* convT = (bf16_t*)alloc((size_t)ND * 3072 * 2);
  bf16_t* wg1T = (bf16_t*)alloc((size_t)ND * 1024 * 2);
  bf16_t* wAllT = (bf16_t*)alloc((size_t)3072 * 2048 * 2);  // [wmv^T; wmg^T; wrg^T]
  float* bAll = (float*)alloc((size_t)3072 * 4);
  float* ctx = (float*)alloc((size_t)NB * 2048 * 4);
  if (off > ws_size) return;  // workspace too small: bail (will fail validation visibly)
  // fused tree-GEMM f32 logits [MCHUNK][3072] = 201MB, aliases h0p+h (dead by tree time)
  float* fbuf = (float*)ws;

  dim3 t256(256), tb32(32, 8);

  // weight conversions (transpose to N x K bf16)
  conv_transpose_k<<<dim3(ND / 32, 3072 / 32), tb32, 0, stream>>>(conv_w, convT, 3072, ND);
  conv_transpose_k<<<dim3(ND / 32, ND / 32), tb32, 0, stream>>>(wg1, wg1T, ND, ND);
  conv_transpose_k<<<dim3(ND / 32, 2048 / 32), tb32, 0, stream>>>(wmv, wAllT, 2048, ND);
  conv_transpose_k<<<dim3(ND / 32, 2048 / 32), tb32, 0, stream>>>(wmg, wAllT + (size_t)1024 * 2048, 2048, ND);
  conv_transpose_k<<<dim3(ND / 32, 2048 / 32), tb32, 0, stream>>>(wrg, wAllT + (size_t)2048 * 2048, 2048, ND);
  concat3_k<<<12, t256, 0, stream>>>(bmv, bmg, brg, bAll);

  zero_pad_k<<<64, t256, 0, stream>>>(h0p);
  embed_k<<<NB * NS, t256, 0, stream>>>(x, emb, pos, h0p);

  // conv as GEMM over contiguous 3*D windows of padded buffer (row remap: +2 per batch)
  gemm_bt<0><<<dim3(8, 512), t256, 0, stream>>>(h0p, convT, conv_b, nullptr, h,
                                                NB * NS, ND, 3072, ND, 11, 2);
  // nodes = h * sigmoid(h@wg1 + bg1)
  gemm_bt<1><<<dim3(8, 512), t256, 0, stream>>>(h, wg1T, bg1, h, nodes,
                                                NB * NS, ND, ND, ND, 0, 0);
  dup_row_k<<<NB, t256, 0, stream>>>(nodes);  // pad odd level: row 2047 := row 2046

  const bf16_t* cur = nodes;
  bf16_t* bufs[2] = {tb0, tb1};
  int pp = 0;
  for (int L = NS; L > 1; L >>= 1) {
    int M = NB * (L / 2);
    for (int c = 0; c < M; c += MCHUNK) {
      int mc = M - c < MCHUNK ? M - c : MCHUNK;
      dim3 g(24, (mc + 127) / 128);
      gemm_bt<2><<<g, t256, 0, stream>>>(cur + (size_t)c * 2048, wAllT, bAll, nullptr, fbuf,
                                         mc, 3072, 2048, 2048, 0, 0);
      tree_combine_k<<<mc, t256, 0, stream>>>(fbuf, cur + (size_t)c * 2048, rms_w,
                                              bufs[pp] + (size_t)c * ND);
    }
    cur = bufs[pp];
    pp ^= 1;
  }

  build_ctx_k<<<NB, t256, 0, stream>>>(cur, nodes, ctx);
  final_proj_k<<<NV / 256, t256, 0, stream>>>(ctx, wp, bp, out);
}

// Round 3
// 2937.452 us; speedup vs baseline: 1.3384x; 1.0208x over previous
//
#include <hip/hip_runtime.h>
#include <stdint.h>

typedef __bf16 bf16_t;
typedef __attribute__((ext_vector_type(8))) __bf16 bf16x8;
typedef __attribute__((ext_vector_type(4))) __bf16 bf16x4;
typedef __attribute__((ext_vector_type(4))) float f32x4;

#define NB 32
#define NS 2048
#define ND 1024
#define NV 32000
#define SP 2050   // padded rows per batch for conv (1 zero row each side)
#define MCHUNK 16384  // max rows per fused tree-GEMM chunk (201MB f32 output)

__device__ __forceinline__ float sigmoid_(float x) { return 1.0f / (1.0f + __expf(-x)); }

__device__ __forceinline__ void gload_lds16(const void* g, void* lds) {
  __builtin_amdgcn_global_load_lds((const __attribute__((address_space(1))) void*)g,
                                   (__attribute__((address_space(3))) void*)lds, 16, 0, 0);
}

// ---------------- prep / elementwise kernels ----------------

__global__ void zero_pad_k(bf16_t* h0p) {
  int i = blockIdx.x;  // 0..63 : 2 pad rows per batch
  int b = i >> 1;
  size_t row = (size_t)b * SP + ((i & 1) ? (SP - 1) : 0);
  bf16x4 z = {};
  *(bf16x4*)(h0p + row * ND + threadIdx.x * 4) = z;
}

__global__ void embed_k(const int* __restrict__ x, const float* __restrict__ emb,
                        const float* __restrict__ pos, bf16_t* __restrict__ h0p) {
  int bs = blockIdx.x;  // 0..NB*NS-1
  int b = bs >> 11, s = bs & (NS - 1);
  int idx = x[bs];
  const float* e = emb + (size_t)idx * ND;
  const float* p = pos + (size_t)s * ND;
  bf16_t* o = h0p + ((size_t)b * SP + s + 1) * ND;
  int d = threadIdx.x * 4;
  f32x4 ev = *(const f32x4*)(e + d);
  f32x4 pv = *(const f32x4*)(p + d);
  bf16x4 ov;
  ov[0] = (bf16_t)(ev[0] + pv[0]);
  ov[1] = (bf16_t)(ev[1] + pv[1]);
  ov[2] = (bf16_t)(ev[2] + pv[2]);
  ov[3] = (bf16_t)(ev[3] + pv[3]);
  *(bf16x4*)(o + d) = ov;
}

// f32 (R x C) -> bf16 (C x R) transpose+convert, 32x32 LDS tiles
__global__ void conv_transpose_k(const float* __restrict__ in, bf16_t* __restrict__ out,
                                 int R, int C) {
  __shared__ float tile[32][33];
  int tc = blockIdx.x * 32, tr = blockIdx.y * 32;
  int tx = threadIdx.x;
  for (int i = threadIdx.y; i < 32; i += 8)
    tile[i][tx] = in[(size_t)(tr + i) * C + tc + tx];
  __syncthreads();
  for (int i = threadIdx.y; i < 32; i += 8)
    out[(size_t)(tc + i) * R + tr + tx] = (bf16_t)tile[tx][i];
}

__global__ void dup_row_k(bf16_t* nodes) {
  int b = blockIdx.x;
  const bf16_t* src = nodes + ((size_t)b * NS + NS - 2) * ND;
  bf16_t* dst = nodes + ((size_t)b * NS + NS - 1) * ND;
  int d = threadIdx.x * 4;
  *(bf16x4*)(dst + d) = *(const bf16x4*)(src + d);
}

__global__ void concat3_k(const float* __restrict__ a, const float* __restrict__ b,
                          const float* __restrict__ c, float* __restrict__ o) {
  int i = blockIdx.x * 256 + threadIdx.x;  // 0..3071
  o[i] = i < 1024 ? a[i] : (i < 2048 ? b[i - 1024] : c[i - 2048]);
}

// ---------------- GEMM: C = A(MxK, lda) @ Bt(NxK)^T + bias ----------------
// 1D grid with XCD-partition swizzle: xcd = id%8 owns gpx N-panels (B L2-resident)
// and a contiguous Y slice (A-panel dup limited to nxg XCDs).
// EPI 0: bf16 store   1: bf16 aux*sigmoid(v) (GLU, aux bf16)   2: f32 store
template <int EPI>
__global__ __launch_bounds__(256, 2) void gemm_bt(
    const bf16_t* __restrict__ A, const bf16_t* __restrict__ Bt,
    const float* __restrict__ bias, const void* aux, void* Cout,
    int M, int N, int K, int lda, int batchShift, int batchPad,
    int gpx, int nxg, int ych) {
  const int tid = threadIdx.x;
  const int lane = tid & 63;
  const int wave = tid >> 6;

  const int id = blockIdx.x;
  const int xcd = id & 7;
  const int j = id >> 3;
  const int xg = xcd % nxg;
  const int ysub = xcd / nxg;
  const int n0 = (xg * gpx + (j % gpx)) * 128;
  const int m0 = (ysub * ych + (j / gpx)) * 128;

  const int waveM = wave >> 1, waveN = wave & 1;

  __shared__ __align__(16) bf16_t sA[128 * 32];
  __shared__ __align__(16) bf16_t sB[128 * 32];

  f32x4 acc[4][4] = {};

  const int sr = tid >> 2;          // 0..63
  const int sc = (tid & 3) * 8;     // k elem offset within 32
  bf16_t* ldsA = &sA[(wave * 16) * 32];  // wave-uniform base
  bf16_t* ldsB = &sB[(wave * 16) * 32];

  for (int k0 = 0; k0 < K; k0 += 32) {
#pragma unroll
    for (int jj = 0; jj < 2; ++jj) {
      int gm = m0 + jj * 64 + sr;
      if (gm > M - 1) gm = M - 1;
      int grow = gm + (gm >> batchShift) * batchPad;  // conv row remap (pad==0 -> identity)
      gload_lds16(A + (size_t)grow * lda + (k0 + sc), ldsA + (size_t)jj * 2048);
      int gn = n0 + jj * 64 + sr;
      gload_lds16(Bt + (size_t)gn * K + (k0 + sc), ldsB + (size_t)jj * 2048);
    }
    __syncthreads();

    bf16x8 af[4], bfr[4];
#pragma unroll
    for (int i = 0; i < 4; ++i) {
      int r = waveM * 64 + i * 16 + (lane & 15);
      af[i] = *(const bf16x8*)&sA[r * 32 + (lane >> 4) * 8];
    }
#pragma unroll
    for (int jj = 0; jj < 4; ++jj) {
      int r = waveN * 64 + jj * 16 + (lane & 15);
      bfr[jj] = *(const bf16x8*)&sB[r * 32 + (lane >> 4) * 8];
    }
#pragma unroll
    for (int i = 0; i < 4; ++i)
#pragma unroll
      for (int jj = 0; jj < 4; ++jj)
        acc[i][jj] = __builtin_amdgcn_mfma_f32_16x16x32_bf16(af[i], bfr[jj], acc[i][jj], 0, 0, 0);
    __syncthreads();
  }

  const int colBase = n0 + waveN * 64 + (lane & 15);
#pragma unroll
  for (int i = 0; i < 4; ++i) {
    const int rowBase = m0 + waveM * 64 + i * 16 + (lane >> 4) * 4;
#pragma unroll
    for (int jj = 0; jj < 4; ++jj) {
      const int col = colBase + jj * 16;
      const float bv = bias[col];
#pragma unroll
      for (int r = 0; r < 4; ++r) {
        const int row = rowBase + r;
        if (row >= M) continue;
        float v = acc[i][jj][r] + bv;
        size_t o = (size_t)row * N + col;
        if constexpr (EPI == 0) {
          ((bf16_t*)Cout)[o] = (bf16_t)v;
        } else if constexpr (EPI == 1) {
          float hh = (float)((const bf16_t*)aux)[o];
          ((bf16_t*)Cout)[o] = (bf16_t)(hh * sigmoid_(v));
        } else {
          ((float*)Cout)[o] = v;
        }
      }
    }
  }
}

// ---------------- tree combine: rmsnorm + gated mix, sigmoids from fused logits ----------------
// fb layout per row: [0,1024) = val, [1024,2048) = mg logit, [2048,3072) = rg logit
__global__ __launch_bounds__(256) void tree_combine_k(
    const float* __restrict__ fb, const bf16_t* __restrict__ cur,
    const float* __restrict__ rms_w, bf16_t* __restrict__ outb) {
  const int m = blockIdx.x;
  const int t = threadIdx.x;
  const int d = t * 4;
  const float* row = fb + (size_t)m * 3072;
  f32x4 v = *(const f32x4*)(row + d);
  f32x4 gl = *(const f32x4*)(row + 1024 + d);
  f32x4 rl = *(const f32x4*)(row + 2048 + d);
  f32x4 vg;
#pragma unroll
  for (int k = 0; k < 4; ++k) vg[k] = v[k] * sigmoid_(gl[k]);
  float ss = vg[0] * vg[0] + vg[1] * vg[1] + vg[2] * vg[2] + vg[3] * vg[3];
#pragma unroll
  for (int o = 32; o > 0; o >>= 1) ss += __shfl_xor(ss, o);
  __shared__ float red[4];
  if ((t & 63) == 0) red[t >> 6] = ss;
  __syncthreads();
  float ms = (red[0] + red[1] + red[2] + red[3]) * (1.0f / ND);
  float scale = rsqrtf(ms + 1.1920929e-07f);
  f32x4 w = *(const f32x4*)(rms_w + d);
  const bf16_t* c0 = cur + (size_t)m * 2048;
  bf16x4 lv = *(const bf16x4*)(c0 + d);
  bf16x4 rv = *(const bf16x4*)(c0 + ND + d);
  bf16x4 o4;
#pragma unroll
  for (int k = 0; k < 4; ++k) {
    float merged = vg[k] * scale * w[k];
    float resid = 0.5f * ((float)lv[k] + (float)rv[k]);
    float g = sigmoid_(rl[k]);
    o4[k] = (bf16_t)(g * merged + (1.0f - g) * resid);
  }
  *(bf16x4*)(outb + (size_t)m * ND + d) = o4;
}

__global__ void build_ctx_k(const bf16_t* __restrict__ root, const bf16_t* __restrict__ nodes,
                            float* __restrict__ ctx) {
  int b = blockIdx.x, t = threadIdx.x;
  const bf16_t* r = root + (size_t)b * ND;
  const bf16_t* l = nodes + ((size_t)b * NS + NS - 2) * ND;
  int d = t * 4;
#pragma unroll
  for (int k = 0; k < 4; ++k) {
    ctx[(size_t)b * 2048 + d + k] = (float)r[d + k];
    ctx[(size_t)b * 2048 + ND + d + k] = (float)l[d + k];
  }
}

// ---------------- final projection in f32: out[b,v] = ctx[b,:]@wp[:,v] + bp[v] ----------------
__global__ __launch_bounds__(256) void final_proj_k(
    const float* __restrict__ ctx, const float* __restrict__ wp,
    const float* __restrict__ bp, float* __restrict__ out) {
  const int v = blockIdx.x * 256 + threadIdx.x;
  float acc[NB];
#pragma unroll
  for (int b = 0; b < NB; ++b) acc[b] = 0.f;
  __shared__ float sctx[NB][128];
  for (int k0 = 0; k0 < 2048; k0 += 128) {
    __syncthreads();
    for (int i = threadIdx.x; i < NB * 128; i += 256) {
      int bb = i >> 7, kk = i & 127;
      sctx[bb][kk] = ctx[(size_t)bb * 2048 + k0 + kk];
    }
    __syncthreads();
    for (int kk = 0; kk < 128; ++kk) {
      float wv = wp[(size_t)(k0 + kk) * NV + v];
#pragma unroll
      for (int b = 0; b < NB; ++b) acc[b] += sctx[b][kk] * wv;
    }
  }
#pragma unroll
  for (int b = 0; b < NB; ++b) out[(size_t)b * NV + v] = acc[b] + bp[v];
}

// ---------------- launch ----------------
extern "C" void kernel_launch(void* const* d_in, const int* in_sizes, int n_in,
                              void* d_out, int out_size, void* d_ws, size_t ws_size,
                              hipStream_t stream) {
  const int* x = (const int*)d_in[0];
  const float* emb = (const float*)d_in[1];
  const float* pos = (const float*)d_in[2];
  const float* conv_w = (const float*)d_in[3];
  const float* conv_b = (const float*)d_in[4];
  const float* wg1 = (const float*)d_in[5];
  const float* bg1 = (const float*)d_in[6];
  const float* wmv = (const float*)d_in[7];
  const float* bmv = (const float*)d_in[8];
  const float* wmg = (const float*)d_in[9];
  const float* bmg = (const float*)d_in[10];
  const float* wrg = (const float*)d_in[11];
  const float* brg = (const float*)d_in[12];
  const float* rms_w = (const float*)d_in[13];
  const float* wp = (const float*)d_in[14];
  const float* bp = (const float*)d_in[15];
  float* out = (float*)d_out;

  char* ws = (char*)d_ws;
  size_t off = 0;
  auto alloc = [&](size_t bytes) -> void* {
    void* p = ws + off;
    off += (bytes + 255) & ~(size_t)255;
    return p;
  };
  bf16_t* h0p = (bf16_t*)alloc((size_t)NB * SP * ND * 2);    // conv input, padded
  bf16_t* h = (bf16_t*)alloc((size_t)NB * NS * ND * 2);      // conv output
  bf16_t* nodes = (bf16_t*)alloc((size_t)NB * NS * ND * 2);  // gated nodes (row 2047 dup'd)
  bf16_t* tb0 = (bf16_t*)alloc((size_t)NB * 1024 * ND * 2);
  bf16_t* tb1 = (bf16_t*)alloc((size_t)NB * 1024 * ND * 2);
  bf16_t* convT = (bf16_t*)alloc((size_t)ND * 3072 * 2);
  bf16_t* wg1T = (bf16_t*)alloc((size_t)ND * 1024 * 2);
  bf16_t* wAllT = (bf16_t*)alloc((size_t)3072 * 2048 * 2);  // [wmv^T; wmg^T; wrg^T]
  float* bAll = (float*)alloc((size_t)3072 * 4);
  float* ctx = (float*)alloc((size_t)NB * 2048 * 4);
  if (off > ws_size) return;  // workspace too small: bail (will fail validation visibly)
  // fused tree-GEMM f32 logits [MCHUNK][3072] = 201MB, aliases h0p+h (dead by tree time)
  float* fbuf = (float*)ws;

  dim3 t256(256), tb32(32, 8);

  // weight conversions (transpose to N x K bf16)
  conv_transpose_k<<<dim3(ND / 32, 3072 / 32), tb32, 0, stream>>>(conv_w, convT, 3072, ND);
  conv_transpose_k<<<dim3(ND / 32, ND / 32), tb32, 0, stream>>>(wg1, wg1T, ND, ND);
  conv_transpose_k<<<dim3(ND / 32, 2048 / 32), tb32, 0, stream>>>(wmv, wAllT, 2048, ND);
  conv_transpose_k<<<dim3(ND / 32, 2048 / 32), tb32, 0, stream>>>(wmg, wAllT + (size_t)1024 * 2048, 2048, ND);
  conv_transpose_k<<<dim3(ND / 32, 2048 / 32), tb32, 0, stream>>>(wrg, wAllT + (size_t)2048 * 2048, 2048, ND);
  concat3_k<<<12, t256, 0, stream>>>(bmv, bmg, brg, bAll);

  zero_pad_k<<<64, t256, 0, stream>>>(h0p);
  embed_k<<<NB * NS, t256, 0, stream>>>(x, emb, pos, h0p);

  // conv as GEMM over contiguous 3*D windows of padded buffer (row remap: +2 per batch)
  // GX=8, GY=512, gpx=4 (nxg=2, nys=4, ych=128)
  gemm_bt<0><<<4096, t256, 0, stream>>>(h0p, convT, conv_b, nullptr, h,
                                        NB * NS, ND, 3072, ND, 11, 2, 4, 2, 128);
  // nodes = h * sigmoid(h@wg1 + bg1)
  gemm_bt<1><<<4096, t256, 0, stream>>>(h, wg1T, bg1, h, nodes,
                                        NB * NS, ND, ND, ND, 0, 0, 4, 2, 128);
  dup_row_k<<<NB, t256, 0, stream>>>(nodes);  // pad odd level: row 2047 := row 2046

  const bf16_t* cur = nodes;
  bf16_t* bufs[2] = {tb0, tb1};
  int pp = 0;
  for (int L = NS; L > 1; L >>= 1) {
    int M = NB * (L / 2);
    for (int c = 0; c < M; c += MCHUNK) {
      int mc = M - c < MCHUNK ? M - c : MCHUNK;
      int GY = (mc + 127) / 128;
      int gpx, nxg, ych;
      if ((GY & 1) == 0) { gpx = 6; nxg = 4; ych = GY / 2; }  // B 3MB/XCD resident, A dup x4
      else               { gpx = 3; nxg = 8; ych = GY; }      // odd GY fallback
      gemm_bt<2><<<24 * GY, t256, 0, stream>>>(cur + (size_t)c * 2048, wAllT, bAll, nullptr,
                                               fbuf, mc, 3072, 2048, 2048, 0, 0, gpx, nxg, ych);
      tree_combine_k<<<mc, t256, 0, stream>>>(fbuf, cur + (size_t)c * 2048, rms_w,
                                              bufs[pp] + (size_t)c * ND);
    }
    cur = bufs[pp];
    pp ^= 1;
  }

  build_ctx_k<<<NB, t256, 0, stream>>>(cur, nodes, ctx);
  final_proj_k<<<NV / 256, t256, 0, stream>>>(ctx, wp, bp, out);
}